// Round 6
// baseline (448.852 us; speedup 1.0000x reference)
//
#include <hip/hip_runtime.h>

// Problem constants
#define DIMM   1024
#define INNER  512
#define HEADS  8
#define DH     64
#define NQ     4096
#define NKV    4096
#define NSPLIT 4
#define KVCHUNK (NKV / NSPLIT)   // 1024
#define QBLK   16
#define MWORDS (NKV / 32)        // 128 mask u32 words per q row
// Fixed softmax max: scores ~ N(0,1); max over 16.7M samples ~ 6. M=12 gives
// huge headroom; p = exp(s-12) keeps full relative precision in bf16.
#define LOG2E  (1.44269504089f)
#define SM_C   (-17.3123404907f)   // -12 * log2(e)

typedef __attribute__((ext_vector_type(8))) short s16x8;
typedef __attribute__((ext_vector_type(4))) short s16x4;
typedef __attribute__((ext_vector_type(4))) float f32x4;
typedef __attribute__((ext_vector_type(4))) unsigned int u32x4;
// may_alias variants for the in-wave P LDS round-trip (u32 store / s16x8 load)
typedef short s16x2a __attribute__((ext_vector_type(2), may_alias));
typedef s16x8 s16x8a __attribute__((may_alias));

// f32 -> bf16 bits, round-to-nearest-even
__device__ __forceinline__ short f2b(float x) {
    unsigned int u = __float_as_uint(x);
    unsigned int r = (u + 0x7fffu + ((u >> 16) & 1u)) >> 16;
    return (short)r;
}

__device__ __forceinline__ float fast_exp2(float x) {
#if __has_builtin(__builtin_amdgcn_exp2f)
    return __builtin_amdgcn_exp2f(x);
#else
    return exp2f(x);
#endif
}

// ---------------------------------------------------------------------------
// K0b: weights -> transposed bf16. Wcat[1536][1024] = [Wq*0.125 | Wk | Wv]^T,
// Wot[1024][512] = Wo^T.
__global__ __launch_bounds__(256) void conv_w(const float* __restrict__ Wq,
                                              const float* __restrict__ Wk,
                                              const float* __restrict__ Wv,
                                              const float* __restrict__ Wo,
                                              short* __restrict__ Wcat,
                                              short* __restrict__ Wot) {
    int idx = blockIdx.x * 256 + threadIdx.x;   // 0 .. 4*524288-1
    int which = idx >> 19;
    int e = idx & 524287;
    if (which == 3) { int k = e >> 10, n = e & 1023; Wot[(size_t)n * INNER + k] = f2b(Wo[e]); }
    else {
        const float* W = (which == 0) ? Wq : (which == 1) ? Wk : Wv;
        float sc = (which == 0) ? 0.125f : 1.0f;
        int k = e >> 9, n = e & 511;
        Wcat[(size_t)(which * 512 + n) * DIMM + k] = f2b(W[e] * sc);
    }
}

// K0c: mask f32 {0,1} -> bitmask. Mb[q][w] bit b = (mask[q][w*32+b] != 0).
__global__ __launch_bounds__(256) void conv_mask(const float* __restrict__ mask,
                                                 unsigned int* __restrict__ Mb) {
    int wg = blockIdx.x * 4 + (threadIdx.x >> 6);   // global wave id, 0..8191
    int l = threadIdx.x & 63;
    for (int itr = 0; itr < 32; ++itr) {
        size_t i = (size_t)wg * 32 + itr;           // 0..262143 chunks of 64 kv
        int q = (int)(i >> 6), c = (int)(i & 63);
        float v = mask[(size_t)q * NKV + c * 64 + l];
        unsigned long long b = __ballot(v != 0.0f);
        if ((l & 31) == 0) Mb[(size_t)q * MWORDS + c * 2 + (l >> 5)] = (unsigned int)(b >> l);
    }
}

// ---------------------------------------------------------------------------
// Fused QKV projection WITH on-the-fly f32->bf16 A conversion.
// 64x128 tile, 768 blocks (3/CU). by<4: Q = x @ Wcat[0:512]^T (scale folded);
// by 4..7: K = y@Wk; by 8..11: V^T.
__global__ __launch_bounds__(256) void gemm_qkv(const float* __restrict__ x,
                                                const float* __restrict__ y,
                                                const short* __restrict__ Wcat,
                                                short* __restrict__ Qb,
                                                short* __restrict__ Kb,
                                                short* __restrict__ Vt) {
    __shared__ __align__(16) short Ash[64 * 40];
    __shared__ __align__(16) short Bsh[128 * 40];
    const int t = threadIdx.x, w = t >> 6, l = t & 63, l15 = l & 15, q4 = l >> 4;
    const int m0 = blockIdx.x * 64;
    const int by = blockIdx.y;
    const int n0 = by * 128;
    const float* A = (by < 4) ? x : y;
    const int wm = (w >> 1) * 32, wn = (w & 1) * 64;
    f32x4 acc[2][4] = {};

    const int arow = t >> 2, aseg = t & 3;           // A: 1 chunk of 8 f32/thread

    for (int ks = 0; ks < DIMM; ks += 32) {
        __syncthreads();
        {   // stage A (f32 -> bf16)
            const f32x4* pa = (const f32x4*)&A[(size_t)(m0 + arow) * DIMM + ks + aseg * 8];
            f32x4 a0 = pa[0], a1 = pa[1];
            s16x8 ab;
#pragma unroll
            for (int j = 0; j < 4; ++j) { ab[j] = f2b(a0[j]); ab[4 + j] = f2b(a1[j]); }
            *(s16x8*)&Ash[arow * 40 + aseg * 8] = ab;
        }
#pragma unroll
        for (int j = 0; j < 2; ++j) {               // stage B (bf16)
            int c = t + j * 256;
            int row = c >> 2, seg = c & 3;
            s16x8 vb = *(const s16x8*)&Wcat[(size_t)(n0 + row) * DIMM + ks + seg * 8];
            *(s16x8*)&Bsh[row * 40 + seg * 8] = vb;
        }
        __syncthreads();
        s16x8 af[2], bf[4];
#pragma unroll
        for (int i = 0; i < 2; ++i) af[i] = *(const s16x8*)&Ash[(wm + i * 16 + l15) * 40 + q4 * 8];
#pragma unroll
        for (int i = 0; i < 4; ++i) bf[i] = *(const s16x8*)&Bsh[(wn + i * 16 + l15) * 40 + q4 * 8];
#pragma unroll
        for (int mi = 0; mi < 2; ++mi)
#pragma unroll
            for (int ni = 0; ni < 4; ++ni)
                acc[mi][ni] = __builtin_amdgcn_mfma_f32_16x16x32_bf16(af[mi], bf[ni], acc[mi][ni], 0, 0, 0);
    }

#pragma unroll
    for (int mi = 0; mi < 2; ++mi)
#pragma unroll
        for (int ni = 0; ni < 4; ++ni)
#pragma unroll
            for (int r = 0; r < 4; ++r) {
                int row = m0 + wm + mi * 16 + q4 * 4 + r;
                int n = n0 + wn + ni * 16 + l15;
                short b = f2b(acc[mi][ni][r]);
                if (n < 512)       Qb[(size_t)row * INNER + n] = b;
                else if (n < 1024) Kb[(size_t)row * INNER + (n - 512)] = b;
                else               Vt[(size_t)(n - 1024) * NKV + row] = b;
            }
}

// ---------------------------------------------------------------------------
// Fused masked attention, barrier-free main loop.
// Block: 256 thr = 4 waves; wave = one head. Wave owns 16 q rows x one KV
// quarter. 2048 blocks -> 8 blocks/CU, launch_bounds(256,8) pins VGPR<=64
// so all 32 waves/CU are resident (grid was the occupancy limiter at QBLK=32).
__global__ __launch_bounds__(256, 8) void attn_fused(const short* __restrict__ Qb,
                                                     const short* __restrict__ Kb,
                                                     const short* __restrict__ Vt,
                                                     const unsigned int* __restrict__ Mb,
                                                     float* __restrict__ Op,
                                                     float* __restrict__ lpart) {
    __shared__ __align__(16) unsigned int Msh[32 * QBLK];   // [kv-word it][q row]
    __shared__ __align__(16) short Psh[4 * QBLK * 40];      // per-wave P [16 q][32+8 kv]
    const int t = threadIdx.x, w = t >> 6, l = t & 63, l15 = l & 15, q4 = l >> 4;
    const int q0 = blockIdx.x * QBLK;
    const int split = blockIdx.y;
    const int h = blockIdx.z * 4 + w;
    const int kv_base = split * KVCHUNK;
    short* Pw = Psh + w * (QBLK * 40);

    // stage mask bits for this block's 16 q rows x 1024 kv (once)
    {
        int it = t & 31, r8 = t >> 5;               // r8 = 0..7
#pragma unroll
        for (int jj = 0; jj < 2; ++jj) {
            int row = r8 + jj * 8;
            Msh[it * QBLK + row] = Mb[(size_t)(q0 + row) * MWORDS + split * 32 + it];
        }
    }

    // Q A-frags in registers: row=l15, k=q4*8+j (d = h*64 + kb*32 + k)
    s16x8 qf[2];
#pragma unroll
    for (int kb = 0; kb < 2; ++kb)
        qf[kb] = *(const s16x8*)&Qb[(size_t)(q0 + l15) * INNER + h * DH + kb * 32 + q4 * 8];

    __syncthreads();   // Msh ready — the ONLY barrier

    f32x4 accO[4] = {};
    float lsum[4] = {};

    for (int it = 0; it < KVCHUNK / 32; ++it) {
        const int kv0 = kv_base + it * 32;
        // K B-frags from global, interleaved kv mapping (tile ni col c -> kv=2c+ni)
        s16x8 kf[2][2];
#pragma unroll
        for (int ni = 0; ni < 2; ++ni)
#pragma unroll
            for (int kb = 0; kb < 2; ++kb)
                kf[ni][kb] = *(const s16x8*)&Kb[(size_t)(kv0 + 2 * l15 + ni) * INNER + h * DH + kb * 32 + q4 * 8];
        // V B-frags from global (Vt: row=d, contiguous kv)
        s16x8 vf[4];
#pragma unroll
        for (int ni = 0; ni < 4; ++ni)
            vf[ni] = *(const s16x8*)&Vt[(size_t)(h * DH + ni * 16 + l15) * NKV + kv0 + q4 * 8];

        // QK^T -> S[16 q][32 kv]
        f32x4 sf[2] = {};
#pragma unroll
        for (int ni = 0; ni < 2; ++ni) {
            sf[ni] = __builtin_amdgcn_mfma_f32_16x16x32_bf16(qf[0], kf[ni][0], sf[ni], 0, 0, 0);
            sf[ni] = __builtin_amdgcn_mfma_f32_16x16x32_bf16(qf[1], kf[ni][1], sf[ni], 0, 0, 0);
        }

        // fixed-max softmax + bitmask + bf16 pack + P write (no shuffles)
        {
            u32x4 w4 = *(const u32x4*)&Msh[it * QBLK + q4 * 4];
#pragma unroll
            for (int r = 0; r < 4; ++r) {
                unsigned int sh = w4[r] >> (2 * l15);          // bits for kv 2*l15, 2*l15+1
                float e0 = fast_exp2(fmaf(sf[0][r], LOG2E, SM_C));
                float e1 = fast_exp2(fmaf(sf[1][r], LOG2E, SM_C));
                float p0 = (sh & 1u) ? 0.0f : e0;
                float p1 = (sh & 2u) ? 0.0f : e1;
                lsum[r] += p0 + p1;
                unsigned int pk;
                asm("v_cvt_pk_bf16_f32 %0, %1, %2" : "=v"(pk) : "v"(p0), "v"(p1));
                *(s16x2a*)&Pw[(q4 * 4 + r) * 40 + 2 * l15] = __builtin_bit_cast(s16x2a, pk);
            }
        }

        // PV: O += P[16,32] @ V[32,64]
        s16x8 pf = (s16x8)(*(const s16x8a*)&Pw[l15 * 40 + q4 * 8]);
#pragma unroll
        for (int ni = 0; ni < 4; ++ni)
            accO[ni] = __builtin_amdgcn_mfma_f32_16x16x32_bf16(pf, vf[ni], accO[ni], 0, 0, 0);
    }

    // unnormalized O partial (fixed M -> partials directly summable)
#pragma unroll
    for (int ni = 0; ni < 4; ++ni)
#pragma unroll
        for (int r = 0; r < 4; ++r) {
            int q = q0 + q4 * 4 + r;
            Op[((size_t)split * NQ + q) * INNER + h * DH + ni * 16 + l15] = accO[ni][r];
        }
    // row-sum reduce across the 16 kv lanes, once per kernel
#pragma unroll
    for (int r = 0; r < 4; ++r) {
        float s = lsum[r];
        s += __shfl_xor(s, 1);
        s += __shfl_xor(s, 2);
        s += __shfl_xor(s, 4);
        s += __shfl_xor(s, 8);
        lsum[r] = s;
    }
    if (l15 == 0) {
#pragma unroll
        for (int r = 0; r < 4; ++r) {
            int q = q0 + q4 * 4 + r;
            lpart[((size_t)split * NQ + q) * HEADS + h] = lsum[r];
        }
    }
}

// ---------------------------------------------------------------------------
// Merge NSPLIT partials (shared fixed M: plain sums) -> AO bf16 [NQ][INNER]
__global__ __launch_bounds__(256) void merge_kernel(const float* __restrict__ Op,
                                                    const float* __restrict__ lpart,
                                                    short* __restrict__ AO) {
    int idx = blockIdx.x * 256 + threadIdx.x;  // 0..262143
    int q = idx >> 6, dc = idx & 63, h = dc >> 3;
    float L = 0.f;
#pragma unroll
    for (int s = 0; s < NSPLIT; ++s) L += lpart[((size_t)s * NQ + q) * HEADS + h];
    f32x4 a0 = {}, a1 = {};
#pragma unroll
    for (int s = 0; s < NSPLIT; ++s) {
        const f32x4* p = (const f32x4*)&Op[((size_t)s * NQ + q) * INNER + dc * 8];
        a0 += p[0];
        a1 += p[1];
    }
    float inv = 1.0f / L;
    s16x8 o;
#pragma unroll
    for (int j = 0; j < 4; ++j) o[j] = f2b(a0[j] * inv);
#pragma unroll
    for (int j = 0; j < 4; ++j) o[4 + j] = f2b(a1[j] * inv);
    *(s16x8*)&AO[(size_t)q * INNER + dc * 8] = o;
}

// ---------------------------------------------------------------------------
// Final projection: out[4096][1024] f32 = AO[4096][512] @ Wot[1024][512]^T
// 64x128 tile, 512 blocks (2/CU).
__global__ __launch_bounds__(256) void gemm_out(const short* __restrict__ A,
                                                const short* __restrict__ Bt,
                                                float* __restrict__ C) {
    __shared__ __align__(16) short Ash[64 * 40];
    __shared__ __align__(16) short Bsh[128 * 40];
    const int t = threadIdx.x, w = t >> 6, l = t & 63, l15 = l & 15, q4 = l >> 4;
    const int m0 = blockIdx.x * 64, n0 = blockIdx.y * 128;
    const int wm = (w >> 1) * 32, wn = (w & 1) * 64;
    f32x4 acc[2][4] = {};
    const int arow = t >> 2, aseg = t & 3;

    for (int ks = 0; ks < INNER; ks += 32) {
        __syncthreads();
        {
            s16x8 va = *(const s16x8*)&A[(size_t)(m0 + arow) * INNER + ks + aseg * 8];
            *(s16x8*)&Ash[arow * 40 + aseg * 8] = va;
        }
#pragma unroll
        for (int j = 0; j < 2; ++j) {
            int c = t + j * 256;
            int row = c >> 2, seg = c & 3;
            s16x8 vb = *(const s16x8*)&Bt[(size_t)(n0 + row) * INNER + ks + seg * 8];
            *(s16x8*)&Bsh[row * 40 + seg * 8] = vb;
        }
        __syncthreads();
        s16x8 af[2], bf[4];
#pragma unroll
        for (int i = 0; i < 2; ++i) af[i] = *(const s16x8*)&Ash[(wm + i * 16 + l15) * 40 + q4 * 8];
#pragma unroll
        for (int i = 0; i < 4; ++i) bf[i] = *(const s16x8*)&Bsh[(wn + i * 16 + l15) * 40 + q4 * 8];
#pragma unroll
        for (int mi = 0; mi < 2; ++mi)
#pragma unroll
            for (int ni = 0; ni < 4; ++ni)
                acc[mi][ni] = __builtin_amdgcn_mfma_f32_16x16x32_bf16(af[mi], bf[ni], acc[mi][ni], 0, 0, 0);
    }

#pragma unroll
    for (int mi = 0; mi < 2; ++mi)
#pragma unroll
        for (int ni = 0; ni < 4; ++ni)
#pragma unroll
            for (int r = 0; r < 4; ++r) {
                int row = m0 + wm + mi * 16 + q4 * 4 + r;
                int col = n0 + wn + ni * 16 + l15;
                C[(size_t)row * DIMM + col] = acc[mi][ni][r];
            }
}

// ---------------------------------------------------------------------------
extern "C" void kernel_launch(void* const* d_in, const int* in_sizes, int n_in,
                              void* d_out, int out_size, void* d_ws, size_t ws_size,
                              hipStream_t stream) {
    const float* x    = (const float*)d_in[0];
    const float* y    = (const float*)d_in[1];
    const float* mask = (const float*)d_in[2];
    const float* Wq   = (const float*)d_in[3];
    const float* Wk   = (const float*)d_in[4];
    const float* Wv   = (const float*)d_in[5];
    const float* Wo   = (const float*)d_in[6];
    float* out = (float*)d_out;

    char* ws = (char*)d_ws;
    float* Op    = (float*)(ws + (size_t)0);              // 32 MB
    short* Qb    = (short*)(ws + ((size_t)32 << 20));     // 4 MB
    short* Kb    = (short*)(ws + ((size_t)36 << 20));     // 4 MB
    short* Vtb   = (short*)(ws + ((size_t)40 << 20));     // 4 MB  Vt[512][4096]
    short* AO    = (short*)(ws + ((size_t)44 << 20));     // 4 MB
    unsigned int* Mb = (unsigned int*)(ws + ((size_t)48 << 20));  // 2 MB
    float* lpart = (float*)(ws + ((size_t)50 << 20));     // 0.5 MB
    short* Wcat  = (short*)(ws + ((size_t)51 << 20));     // 3 MB
    short* Wot   = (short*)(ws + ((size_t)54 << 20));     // 1 MB

    hipLaunchKernelGGL(conv_w,    dim3(8192), dim3(256), 0, stream, Wq, Wk, Wv, Wo, Wcat, Wot);
    hipLaunchKernelGGL(conv_mask, dim3(2048), dim3(256), 0, stream, mask, Mb);
    hipLaunchKernelGGL(gemm_qkv,  dim3(64, 12), dim3(256), 0, stream, x, y, Wcat, Qb, Kb, Vtb);
    hipLaunchKernelGGL(attn_fused, dim3(NQ / QBLK, NSPLIT, 2), dim3(256), 0, stream,
                       Qb, Kb, Vtb, Mb, Op, lpart);
    hipLaunchKernelGGL(merge_kernel, dim3(1024), dim3(256), 0, stream, Op, lpart, AO);
    hipLaunchKernelGGL(gemm_out,  dim3(64, 8), dim3(256), 0, stream, AO, Wot, out);
}

// Round 9
// 332.606 us; speedup vs baseline: 1.3495x; 1.3495x over previous
//
#include <hip/hip_runtime.h>

// Problem constants
#define DIMM   1024
#define INNER  512
#define HEADS  8
#define DH     64
#define NQ     4096
#define NKV    4096
#define NSPLIT 4
#define KVCHUNK (NKV / NSPLIT)   // 1024
#define QBLK   32
#define MWORDS (NKV / 32)        // 128 mask u32 words per q row
// Fixed softmax max: scores ~ N(0,1); max over 16.7M samples ~ 6. M=12 gives
// huge headroom; p = exp(s-12) keeps full relative precision in bf16.
#define LOG2E  (1.44269504089f)
#define SM_C   (-17.3123404907f)   // -12 * log2(e)

typedef __attribute__((ext_vector_type(8))) short s16x8;
typedef __attribute__((ext_vector_type(4))) short s16x4;
typedef __attribute__((ext_vector_type(4))) float f32x4;
typedef __attribute__((ext_vector_type(4))) unsigned int u32x4;
// may_alias variants for the in-wave P LDS round-trip (u32 store / s16x8 load)
typedef short s16x2a __attribute__((ext_vector_type(2), may_alias));
typedef s16x8 s16x8a __attribute__((may_alias));

// f32 -> bf16 bits, round-to-nearest-even
__device__ __forceinline__ short f2b(float x) {
    unsigned int u = __float_as_uint(x);
    unsigned int r = (u + 0x7fffu + ((u >> 16) & 1u)) >> 16;
    return (short)r;
}

__device__ __forceinline__ float fast_exp2(float x) {
#if __has_builtin(__builtin_amdgcn_exp2f)
    return __builtin_amdgcn_exp2f(x);
#else
    return exp2f(x);
#endif
}

// ---------------------------------------------------------------------------
// K0b: weights -> transposed bf16. Wcat[1536][1024] = [Wq*0.125 | Wk | Wv]^T,
// Wot[1024][512] = Wo^T.
__global__ __launch_bounds__(256) void conv_w(const float* __restrict__ Wq,
                                              const float* __restrict__ Wk,
                                              const float* __restrict__ Wv,
                                              const float* __restrict__ Wo,
                                              short* __restrict__ Wcat,
                                              short* __restrict__ Wot) {
    int idx = blockIdx.x * 256 + threadIdx.x;   // 0 .. 4*524288-1
    int which = idx >> 19;
    int e = idx & 524287;
    if (which == 3) { int k = e >> 10, n = e & 1023; Wot[(size_t)n * INNER + k] = f2b(Wo[e]); }
    else {
        const float* W = (which == 0) ? Wq : (which == 1) ? Wk : Wv;
        float sc = (which == 0) ? 0.125f : 1.0f;
        int k = e >> 9, n = e & 511;
        Wcat[(size_t)(which * 512 + n) * DIMM + k] = f2b(W[e] * sc);
    }
}

// K0c: mask f32 {0,1} -> bitmask. Mb[q][w] bit b = (mask[q][w*32+b] != 0).
__global__ __launch_bounds__(256) void conv_mask(const float* __restrict__ mask,
                                                 unsigned int* __restrict__ Mb) {
    int wg = blockIdx.x * 4 + (threadIdx.x >> 6);   // global wave id, 0..8191
    int l = threadIdx.x & 63;
    for (int itr = 0; itr < 32; ++itr) {
        size_t i = (size_t)wg * 32 + itr;           // 0..262143 chunks of 64 kv
        int q = (int)(i >> 6), c = (int)(i & 63);
        float v = mask[(size_t)q * NKV + c * 64 + l];
        unsigned long long b = __ballot(v != 0.0f);
        if ((l & 31) == 0) Mb[(size_t)q * MWORDS + c * 2 + (l >> 5)] = (unsigned int)(b >> l);
    }
}

// ---------------------------------------------------------------------------
// Fused QKV projection WITH on-the-fly f32->bf16 A conversion.
// 64x128 tile, 768 blocks (3/CU). by<4: Q = x @ Wcat[0:512]^T (scale folded);
// by 4..7: K = y@Wk; by 8..11: V^T.
__global__ __launch_bounds__(256) void gemm_qkv(const float* __restrict__ x,
                                                const float* __restrict__ y,
                                                const short* __restrict__ Wcat,
                                                short* __restrict__ Qb,
                                                short* __restrict__ Kb,
                                                short* __restrict__ Vt) {
    __shared__ __align__(16) short Ash[64 * 40];
    __shared__ __align__(16) short Bsh[128 * 40];
    const int t = threadIdx.x, w = t >> 6, l = t & 63, l15 = l & 15, q4 = l >> 4;
    const int m0 = blockIdx.x * 64;
    const int by = blockIdx.y;
    const int n0 = by * 128;
    const float* A = (by < 4) ? x : y;
    const int wm = (w >> 1) * 32, wn = (w & 1) * 64;
    f32x4 acc[2][4] = {};

    const int arow = t >> 2, aseg = t & 3;           // A: 1 chunk of 8 f32/thread

    for (int ks = 0; ks < DIMM; ks += 32) {
        __syncthreads();
        {   // stage A (f32 -> bf16)
            const f32x4* pa = (const f32x4*)&A[(size_t)(m0 + arow) * DIMM + ks + aseg * 8];
            f32x4 a0 = pa[0], a1 = pa[1];
            s16x8 ab;
#pragma unroll
            for (int j = 0; j < 4; ++j) { ab[j] = f2b(a0[j]); ab[4 + j] = f2b(a1[j]); }
            *(s16x8*)&Ash[arow * 40 + aseg * 8] = ab;
        }
#pragma unroll
        for (int j = 0; j < 2; ++j) {               // stage B (bf16)
            int c = t + j * 256;
            int row = c >> 2, seg = c & 3;
            s16x8 vb = *(const s16x8*)&Wcat[(size_t)(n0 + row) * DIMM + ks + seg * 8];
            *(s16x8*)&Bsh[row * 40 + seg * 8] = vb;
        }
        __syncthreads();
        s16x8 af[2], bf[4];
#pragma unroll
        for (int i = 0; i < 2; ++i) af[i] = *(const s16x8*)&Ash[(wm + i * 16 + l15) * 40 + q4 * 8];
#pragma unroll
        for (int i = 0; i < 4; ++i) bf[i] = *(const s16x8*)&Bsh[(wn + i * 16 + l15) * 40 + q4 * 8];
#pragma unroll
        for (int mi = 0; mi < 2; ++mi)
#pragma unroll
            for (int ni = 0; ni < 4; ++ni)
                acc[mi][ni] = __builtin_amdgcn_mfma_f32_16x16x32_bf16(af[mi], bf[ni], acc[mi][ni], 0, 0, 0);
    }

#pragma unroll
    for (int mi = 0; mi < 2; ++mi)
#pragma unroll
        for (int ni = 0; ni < 4; ++ni)
#pragma unroll
            for (int r = 0; r < 4; ++r) {
                int row = m0 + wm + mi * 16 + q4 * 4 + r;
                int n = n0 + wn + ni * 16 + l15;
                short b = f2b(acc[mi][ni][r]);
                if (n < 512)       Qb[(size_t)row * INNER + n] = b;
                else if (n < 1024) Kb[(size_t)row * INNER + (n - 512)] = b;
                else               Vt[(size_t)(n - 1024) * NKV + row] = b;
            }
}

// ---------------------------------------------------------------------------
// Fused masked attention, barrier-free main loop (round-3 structure, QBLK=32,
// NO occupancy pin — launch_bounds(256,8) forced VGPR=32 + full spill, 2x slower).
// XCD-pinned 1-D grid: b = qi*8 + (split*2+hgroup). Dispatch round-robins
// XCDs mod 8, so all blocks sharing (split,hgroup) — i.e. the same 1MB K/V
// slice — land on ONE XCD's 4MB L2 (was: 8MB+ working set thrashing it,
// FETCH 36MB vs 14MB ideal).
__global__ __launch_bounds__(256) void attn_fused(const short* __restrict__ Qb,
                                                  const short* __restrict__ Kb,
                                                  const short* __restrict__ Vt,
                                                  const unsigned int* __restrict__ Mb,
                                                  float* __restrict__ Op,
                                                  float* __restrict__ lpart) {
    __shared__ __align__(16) unsigned int Msh[32 * 32];   // [kv-word it][q row]
    __shared__ __align__(16) short Psh[4 * 32 * 40];      // per-wave P [32 q][32+8 kv]
    const int t = threadIdx.x, w = t >> 6, l = t & 63, l15 = l & 15, q4 = l >> 4;
    const int b = blockIdx.x;
    const int sh8 = b & 7;
    const int split = sh8 >> 1;
    const int h = (sh8 & 1) * 4 + w;
    const int q0 = (b >> 3) * QBLK;
    const int kv_base = split * KVCHUNK;
    short* Pw = Psh + w * (32 * 40);

    // stage mask bits for this block's 32 q rows x 1024 kv (once)
    {
        int it = t & 31, r8 = t >> 5;
#pragma unroll
        for (int jj = 0; jj < 4; ++jj) {
            int row = r8 + jj * 8;
            Msh[it * 32 + row] = Mb[(size_t)(q0 + row) * MWORDS + split * 32 + it];
        }
    }

    // Q A-frags in registers: row=l15, k=q4*8+j (d = h*64 + kb*32 + k)
    s16x8 qf[2][2];
#pragma unroll
    for (int mi = 0; mi < 2; ++mi)
#pragma unroll
        for (int kb = 0; kb < 2; ++kb)
            qf[mi][kb] = *(const s16x8*)&Qb[(size_t)(q0 + mi * 16 + l15) * INNER + h * DH + kb * 32 + q4 * 8];

    __syncthreads();   // Msh ready — the ONLY barrier

    f32x4 accO[2][4] = {};
    float lsum[2][4] = {};

#pragma unroll 2
    for (int it = 0; it < KVCHUNK / 32; ++it) {
        const int kv0 = kv_base + it * 32;
        // K B-frags from global, interleaved kv mapping (tile ni col c -> kv=2c+ni)
        s16x8 kf[2][2];
#pragma unroll
        for (int ni = 0; ni < 2; ++ni)
#pragma unroll
            for (int kb = 0; kb < 2; ++kb)
                kf[ni][kb] = *(const s16x8*)&Kb[(size_t)(kv0 + 2 * l15 + ni) * INNER + h * DH + kb * 32 + q4 * 8];
        // V B-frags from global (Vt: row=d, contiguous kv)
        s16x8 vf[4];
#pragma unroll
        for (int ni = 0; ni < 4; ++ni)
            vf[ni] = *(const s16x8*)&Vt[(size_t)(h * DH + ni * 16 + l15) * NKV + kv0 + q4 * 8];

        // QK^T -> S[32 q][32 kv]
        f32x4 sf[2][2] = {};
#pragma unroll
        for (int mi = 0; mi < 2; ++mi)
#pragma unroll
            for (int ni = 0; ni < 2; ++ni) {
                sf[mi][ni] = __builtin_amdgcn_mfma_f32_16x16x32_bf16(qf[mi][0], kf[ni][0], sf[mi][ni], 0, 0, 0);
                sf[mi][ni] = __builtin_amdgcn_mfma_f32_16x16x32_bf16(qf[mi][1], kf[ni][1], sf[mi][ni], 0, 0, 0);
            }

        // fixed-max softmax + bitmask + bf16 pack + P write (no shuffles)
#pragma unroll
        for (int mi = 0; mi < 2; ++mi) {
            u32x4 w4 = *(const u32x4*)&Msh[it * 32 + mi * 16 + q4 * 4];
#pragma unroll
            for (int r = 0; r < 4; ++r) {
                unsigned int shb = w4[r] >> (2 * l15);         // bits for kv 2*l15, 2*l15+1
                float e0 = fast_exp2(fmaf(sf[mi][0][r], LOG2E, SM_C));
                float e1 = fast_exp2(fmaf(sf[mi][1][r], LOG2E, SM_C));
                float p0 = (shb & 1u) ? 0.0f : e0;
                float p1 = (shb & 2u) ? 0.0f : e1;
                lsum[mi][r] += p0 + p1;
                unsigned int pk;
                asm("v_cvt_pk_bf16_f32 %0, %1, %2" : "=v"(pk) : "v"(p0), "v"(p1));
                *(s16x2a*)&Pw[(mi * 16 + q4 * 4 + r) * 40 + 2 * l15] = __builtin_bit_cast(s16x2a, pk);
            }
        }

        // PV: O += P[32,32] @ V[32,64]  (in-wave LDS round-trip, program order)
        s16x8 pf[2];
#pragma unroll
        for (int mi = 0; mi < 2; ++mi)
            pf[mi] = (s16x8)(*(const s16x8a*)&Pw[(mi * 16 + l15) * 40 + q4 * 8]);
#pragma unroll
        for (int mi = 0; mi < 2; ++mi)
#pragma unroll
            for (int ni = 0; ni < 4; ++ni)
                accO[mi][ni] = __builtin_amdgcn_mfma_f32_16x16x32_bf16(pf[mi], vf[ni], accO[mi][ni], 0, 0, 0);
    }

    // unnormalized O partial (fixed M -> partials directly summable)
#pragma unroll
    for (int mi = 0; mi < 2; ++mi)
#pragma unroll
        for (int ni = 0; ni < 4; ++ni)
#pragma unroll
            for (int r = 0; r < 4; ++r) {
                int q = q0 + mi * 16 + q4 * 4 + r;
                Op[((size_t)split * NQ + q) * INNER + h * DH + ni * 16 + l15] = accO[mi][ni][r];
            }
    // row-sum reduce across the 16 kv lanes, once per kernel
#pragma unroll
    for (int mi = 0; mi < 2; ++mi)
#pragma unroll
        for (int r = 0; r < 4; ++r) {
            float s = lsum[mi][r];
            s += __shfl_xor(s, 1);
            s += __shfl_xor(s, 2);
            s += __shfl_xor(s, 4);
            s += __shfl_xor(s, 8);
            lsum[mi][r] = s;
        }
    if (l15 == 0) {
#pragma unroll
        for (int mi = 0; mi < 2; ++mi)
#pragma unroll
            for (int r = 0; r < 4; ++r) {
                int q = q0 + mi * 16 + q4 * 4 + r;
                lpart[((size_t)split * NQ + q) * HEADS + h] = lsum[mi][r];
            }
    }
}

// ---------------------------------------------------------------------------
// Merge NSPLIT partials (shared fixed M: plain sums) -> AO bf16 [NQ][INNER]
__global__ __launch_bounds__(256) void merge_kernel(const float* __restrict__ Op,
                                                    const float* __restrict__ lpart,
                                                    short* __restrict__ AO) {
    int idx = blockIdx.x * 256 + threadIdx.x;  // 0..262143
    int q = idx >> 6, dc = idx & 63, h = dc >> 3;
    float L = 0.f;
#pragma unroll
    for (int s = 0; s < NSPLIT; ++s) L += lpart[((size_t)s * NQ + q) * HEADS + h];
    f32x4 a0 = {}, a1 = {};
#pragma unroll
    for (int s = 0; s < NSPLIT; ++s) {
        const f32x4* p = (const f32x4*)&Op[((size_t)s * NQ + q) * INNER + dc * 8];
        a0 += p[0];
        a1 += p[1];
    }
    float inv = 1.0f / L;
    s16x8 o;
#pragma unroll
    for (int j = 0; j < 4; ++j) o[j] = f2b(a0[j] * inv);
#pragma unroll
    for (int j = 0; j < 4; ++j) o[4 + j] = f2b(a1[j] * inv);
    *(s16x8*)&AO[(size_t)q * INNER + dc * 8] = o;
}

// ---------------------------------------------------------------------------
// Final projection: out[4096][1024] f32 = AO[4096][512] @ Wot[1024][512]^T
// 64x128 tile, 512 blocks (2/CU).
__global__ __launch_bounds__(256) void gemm_out(const short* __restrict__ A,
                                                const short* __restrict__ Bt,
                                                float* __restrict__ C) {
    __shared__ __align__(16) short Ash[64 * 40];
    __shared__ __align__(16) short Bsh[128 * 40];
    const int t = threadIdx.x, w = t >> 6, l = t & 63, l15 = l & 15, q4 = l >> 4;
    const int m0 = blockIdx.x * 64, n0 = blockIdx.y * 128;
    const int wm = (w >> 1) * 32, wn = (w & 1) * 64;
    f32x4 acc[2][4] = {};
    const int arow = t >> 2, aseg = t & 3;

    for (int ks = 0; ks < INNER; ks += 32) {
        __syncthreads();
        {
            s16x8 va = *(const s16x8*)&A[(size_t)(m0 + arow) * INNER + ks + aseg * 8];
            *(s16x8*)&Ash[arow * 40 + aseg * 8] = va;
        }
#pragma unroll
        for (int j = 0; j < 2; ++j) {
            int c = t + j * 256;
            int row = c >> 2, seg = c & 3;
            s16x8 vb = *(const s16x8*)&Bt[(size_t)(n0 + row) * INNER + ks + seg * 8];
            *(s16x8*)&Bsh[row * 40 + seg * 8] = vb;
        }
        __syncthreads();
        s16x8 af[2], bf[4];
#pragma unroll
        for (int i = 0; i < 2; ++i) af[i] = *(const s16x8*)&Ash[(wm + i * 16 + l15) * 40 + q4 * 8];
#pragma unroll
        for (int i = 0; i < 4; ++i) bf[i] = *(const s16x8*)&Bsh[(wn + i * 16 + l15) * 40 + q4 * 8];
#pragma unroll
        for (int mi = 0; mi < 2; ++mi)
#pragma unroll
            for (int ni = 0; ni < 4; ++ni)
                acc[mi][ni] = __builtin_amdgcn_mfma_f32_16x16x32_bf16(af[mi], bf[ni], acc[mi][ni], 0, 0, 0);
    }

#pragma unroll
    for (int mi = 0; mi < 2; ++mi)
#pragma unroll
        for (int ni = 0; ni < 4; ++ni)
#pragma unroll
            for (int r = 0; r < 4; ++r) {
                int row = m0 + wm + mi * 16 + q4 * 4 + r;
                int col = n0 + wn + ni * 16 + l15;
                C[(size_t)row * DIMM + col] = acc[mi][ni][r];
            }
}

// ---------------------------------------------------------------------------
extern "C" void kernel_launch(void* const* d_in, const int* in_sizes, int n_in,
                              void* d_out, int out_size, void* d_ws, size_t ws_size,
                              hipStream_t stream) {
    const float* x    = (const float*)d_in[0];
    const float* y    = (const float*)d_in[1];
    const float* mask = (const float*)d_in[2];
    const float* Wq   = (const float*)d_in[3];
    const float* Wk   = (const float*)d_in[4];
    const float* Wv   = (const float*)d_in[5];
    const float* Wo   = (const float*)d_in[6];
    float* out = (float*)d_out;

    char* ws = (char*)d_ws;
    float* Op    = (float*)(ws + (size_t)0);              // 32 MB
    short* Qb    = (short*)(ws + ((size_t)32 << 20));     // 4 MB
    short* Kb    = (short*)(ws + ((size_t)36 << 20));     // 4 MB
    short* Vtb   = (short*)(ws + ((size_t)40 << 20));     // 4 MB  Vt[512][4096]
    short* AO    = (short*)(ws + ((size_t)44 << 20));     // 4 MB
    unsigned int* Mb = (unsigned int*)(ws + ((size_t)48 << 20));  // 2 MB
    float* lpart = (float*)(ws + ((size_t)50 << 20));     // 0.5 MB
    short* Wcat  = (short*)(ws + ((size_t)51 << 20));     // 3 MB
    short* Wot   = (short*)(ws + ((size_t)54 << 20));     // 1 MB

    hipLaunchKernelGGL(conv_w,    dim3(8192), dim3(256), 0, stream, Wq, Wk, Wv, Wo, Wcat, Wot);
    hipLaunchKernelGGL(conv_mask, dim3(2048), dim3(256), 0, stream, mask, Mb);
    hipLaunchKernelGGL(gemm_qkv,  dim3(64, 12), dim3(256), 0, stream, x, y, Wcat, Qb, Kb, Vtb);
    hipLaunchKernelGGL(attn_fused, dim3((NQ / QBLK) * NSPLIT * 2), dim3(256), 0, stream,
                       Qb, Kb, Vtb, Mb, Op, lpart);
    hipLaunchKernelGGL(merge_kernel, dim3(1024), dim3(256), 0, stream, Op, lpart, AO);
    hipLaunchKernelGGL(gemm_out,  dim3(64, 8), dim3(256), 0, stream, AO, Wot, out);
}